// Round 9
// baseline (808.647 us; speedup 1.0000x reference)
//
#include <hip/hip_runtime.h>

#define F 64
#define N_NODES 8192
#define E_EDGES 262144
#define EF 32
#define HID 64
#define INV_AVG (1.0f/32.0f)
#define INV_SQRT3 0.57735026918962576f
#define INV_SQRT2 0.70710678118654752f

__device__ __forceinline__ float silu(float x) {
    return x / (1.0f + __expf(-x));
}

// Compiler-only memory fence: orders LDS ops within a wave's program order
// (HW executes same-wave DS ops in order; lanes are lockstep). No instruction.
#define WAVE_FENCE() asm volatile("" ::: "memory")

// ---------------------------------------------------------------------------
// Sort prologue: counting sort of edges by rcv.
// ---------------------------------------------------------------------------
__global__ __launch_bounds__(256) void hist_kernel(
    const int* __restrict__ edge_index, int* __restrict__ cnt) {
    const int e = blockIdx.x * 256 + threadIdx.x;
    atomicAdd(&cnt[edge_index[E_EDGES + e]], 1);
}

__global__ __launch_bounds__(256) void scan_kernel(
    const int* __restrict__ cnt, int* __restrict__ offs) {
    __shared__ int part[256];
    const int t = threadIdx.x;
    int local[32];
    int s = 0;
#pragma unroll
    for (int i = 0; i < 32; ++i) { local[i] = s; s += cnt[t * 32 + i]; }
    part[t] = s;
    __syncthreads();
    for (int d = 1; d < 256; d <<= 1) {
        int v = (t >= d) ? part[t - d] : 0;
        __syncthreads();
        part[t] += v;
        __syncthreads();
    }
    const int prefix = (t == 0) ? 0 : part[t - 1];
#pragma unroll
    for (int i = 0; i < 32; ++i) offs[t * 32 + i] = prefix + local[i];
}

__global__ __launch_bounds__(256) void perm_kernel(
    const int* __restrict__ edge_index, int* __restrict__ offs,
    int* __restrict__ perm) {
    const int e = blockIdx.x * 256 + threadIdx.x;
    const int pos = atomicAdd(&offs[edge_index[E_EDGES + e]], 1);
    perm[pos] = e;
}

// ---------------------------------------------------------------------------
// Kernel: node transforms.  NS = s@Wsc, SUP = s@Wup_s, VUP[n][c][g] = v@Wup_v
// ---------------------------------------------------------------------------
__global__ __launch_bounds__(64) void node_kernel(
    const float* __restrict__ node_feats,
    const float* __restrict__ Wsc,
    const float* __restrict__ Wup_s,
    const float* __restrict__ Wup_v,
    float* __restrict__ NS,
    float* __restrict__ SUP,
    float* __restrict__ VUP) {
    const int n = blockIdx.x;
    const int g = threadIdx.x;
    __shared__ float s_lds[64];
    __shared__ float v_lds[3][64];

    const float* nf = node_feats + (size_t)n * 256;
    s_lds[g] = nf[g];
    v_lds[0][g] = nf[64 + g * 3 + 0];
    v_lds[1][g] = nf[64 + g * 3 + 1];
    v_lds[2][g] = nf[64 + g * 3 + 2];
    __syncthreads();

    float ns = 0.f, su = 0.f, vu0 = 0.f, vu1 = 0.f, vu2 = 0.f;
#pragma unroll 8
    for (int k = 0; k < 64; ++k) {
        const float sk = s_lds[k];
        ns += sk * Wsc[k * 64 + g];
        su += sk * Wup_s[k * 64 + g];
        const float w = Wup_v[k * 64 + g];
        vu0 += v_lds[0][k] * w;
        vu1 += v_lds[1][k] * w;
        vu2 += v_lds[2][k] * w;
    }
    NS[n * 64 + g] = ns;
    SUP[n * 64 + g] = su;
    VUP[(n * 3 + 0) * 64 + g] = vu0;
    VUP[(n * 3 + 1) * 64 + g] = vu1;
    VUP[(n * 3 + 2) * 64 + g] = vu2;
}

// ---------------------------------------------------------------------------
// Fused edge kernel: 256-thread block = 4 INDEPENDENT waves, each owning 64
// edges and a private LDS region (4 x 10240B = 40960B -> exactly 4 blocks/CU
// = 16 waves/CU). NO s_barrier — waves decoupled; cross-lane hand-offs inside
// a wave use WAVE_FENCE() (compile-time order, lockstep lanes, in-order DS).
// VGPR: ~100 live set, __launch_bounds__(256,2) allows it (empirical cap
// model: 256/min_waves). k-loops reading acc[k] fully unrolled (rule #20).
// ---------------------------------------------------------------------------
#define BATCH 4
#define WPB 4
__global__ __launch_bounds__(256, 2) void edge_kernel(
    const float* __restrict__ edge_attrs,
    const float* __restrict__ edge_feats,
    const float* __restrict__ lengths,
    const int*   __restrict__ edge_index,
    const int*   __restrict__ perm,
    const float* __restrict__ W1, const float* __restrict__ b1,
    const float* __restrict__ W2, const float* __restrict__ b2,
    const float* __restrict__ W3,
    const float* __restrict__ NS,
    const float* __restrict__ SUP,
    const float* __restrict__ VUP,
    float* __restrict__ M0,
    float* __restrict__ M1) {
    const int w    = threadIdx.x >> 6;   // wave id 0..3 (independent)
    const int lane = threadIdx.x & 63;
    const int e0   = (blockIdx.x * WPB + w) * 64;

    __shared__ float xt[WPB][64][33];    // per-wave staging/transpose/stash
    __shared__ int   snd_s[WPB][64];
    __shared__ int   rcv_s[WPB][64];
    __shared__ int   pe_s[WPB][64];
    __shared__ float attr_s[WPB][4][64];

    // ---- edge metadata (sorted order) ----
    const int pe  = perm[e0 + lane];
    const int snd = edge_index[pe];
    const int rcv = edge_index[E_EDGES + pe];
    const float len = lengths[pe];
    const float4 a4 = ((const float4*)edge_attrs)[pe];
    snd_s[w][lane] = snd;
    rcv_s[w][lane] = rcv;
    pe_s[w][lane]  = pe;
    attr_s[w][0][lane] = a4.x;
    attr_s[w][1][lane] = a4.y;
    attr_s[w][2][lane] = a4.z;
    attr_s[w][3][lane] = a4.w;
    WAVE_FENCE();

    const int kk0 = lane & 31;
    const int jh  = lane >> 5;

    // ---- layer 1: 161 -> 64, acc[g] in VGPRs ----
    float acc[64];
#pragma unroll
    for (int g = 0; g < 64; ++g) acc[g] = b1[g];

#pragma unroll
    for (int t = 0; t < 5; ++t) {
        // stage 64 edges x 32 features, 4-wide load batching
        for (int i0 = 0; i0 < 32; i0 += BATCH) {
            float tmp[BATCH];
#pragma unroll
            for (int u = 0; u < BATCH; ++u) {
                const int j = 2 * (i0 + u) + jh;
                if (t < 4) {
                    const int node = (t < 2) ? snd_s[w][j] : rcv_s[w][j];
                    tmp[u] = NS[node * 64 + (t & 1) * 32 + kk0];
                } else {
                    tmp[u] = edge_feats[(size_t)pe_s[w][j] * EF + kk0];
                }
            }
#pragma unroll
            for (int u = 0; u < BATCH; ++u) xt[w][2 * (i0 + u) + jh][kk0] = tmp[u];
        }
        WAVE_FENCE();
        // kk rolled is fine: acc[g] indices are static, xt is LDS.
        for (int kk = 0; kk < 32; ++kk) {
            const float x = xt[w][lane][kk];
            const float* wr = W1 + (t * 32 + kk) * 64;
#pragma unroll
            for (int g = 0; g < 64; ++g) acc[g] += x * wr[g];
        }
        WAVE_FENCE();
    }
    {   // k = 160: length (lane-local)
        const float* wr = W1 + 160 * 64;
#pragma unroll
        for (int g = 0; g < 64; ++g) acc[g] += len * wr[g];
    }
#pragma unroll
    for (int k = 0; k < 64; ++k) acc[k] = silu(acc[k]);   // h1 in regs

    // ---- layer 2: 64 -> 64 in two 32-chunks (lane-local LDS stash) ----
    for (int ch = 0; ch < 2; ++ch) {
        const int gbase = (ch == 0) ? 32 : 0;
        const float* W2b = W2 + gbase;
        float acc2[32];
#pragma unroll
        for (int gg = 0; gg < 32; ++gg) acc2[gg] = b2[gbase + gg];
#pragma unroll
        for (int k = 0; k < 64; ++k) {          // FULL unroll: acc[k] static
            const float hk = acc[k];
#pragma unroll
            for (int gg = 0; gg < 32; ++gg) acc2[gg] += hk * W2b[k * 64 + gg];
        }
        if (ch == 0) {
#pragma unroll
            for (int gg = 0; gg < 32; ++gg) xt[w][lane][gg] = silu(acc2[gg]);
        } else {
#pragma unroll
            for (int gg = 0; gg < 32; ++gg) acc[gg] = silu(acc2[gg]);
#pragma unroll
            for (int gg = 0; gg < 32; ++gg) acc[32 + gg] = xt[w][lane][gg];
        }
    }
    // acc[] now holds h2.

    // ---- layer 3 (ten 32-wide chunks) + transpose + run-aggregated scatter
    const int halfsel = lane >> 5;
    const int gl      = lane & 31;

    for (int c = 0; c < 5; ++c) {
        for (int hh = 0; hh < 2; ++hh) {
            const float* W3b = W3 + c * 64 + hh * 32;
            float acc3[32];
#pragma unroll
            for (int gg = 0; gg < 32; ++gg) acc3[gg] = 0.f;
#pragma unroll
            for (int k = 0; k < 64; ++k) {      // FULL unroll: acc[k] static
                const float hk = acc[k];
#pragma unroll
                for (int gg = 0; gg < 32; ++gg) acc3[gg] += hk * W3b[k * 320 + gg];
            }
            // transpose to lane=feature
            WAVE_FENCE();
#pragma unroll
            for (int gg = 0; gg < 32; ++gg) xt[w][lane][gg] = acc3[gg];
            WAVE_FENCE();

            const int g = hh * 32 + gl;
            int   cur = -1;
            float r0 = 0.f, r1 = 0.f, r2 = 0.f;
            for (int u0 = 0; u0 < 32; u0 += BATCH) {
                // batched gather phase
                float ld0[BATCH], ld1[BATCH], ld2[BATCH];
#pragma unroll
                for (int u = 0; u < BATCH; ++u) {
                    const int j = 32 * halfsel + u0 + u;
                    const int sndj = snd_s[w][j];
                    if (c == 0 || c == 2) {
                        ld0[u] = SUP[sndj * 64 + g];
                    } else {
                        ld0[u] = VUP[(sndj * 3 + 0) * 64 + g];
                        ld1[u] = VUP[(sndj * 3 + 1) * 64 + g];
                        ld2[u] = VUP[(sndj * 3 + 2) * 64 + g];
                    }
                }
                // compute phase
#pragma unroll
                for (int u = 0; u < BATCH; ++u) {
                    const int j = 32 * halfsel + u0 + u;
                    const int rcvj = rcv_s[w][j];
                    if (rcvj != cur) {
                        if (cur >= 0) {
                            if (c == 0)      atomicAdd(&M0[(size_t)cur * 128 + g], r0);
                            else if (c == 1) atomicAdd(&M0[(size_t)cur * 128 + 64 + g], r0);
                            else {
                                float* M1r = M1 + (size_t)cur * 576;
                                const int off = (c == 2) ? 0 : (c == 3) ? 64 : 128;
                                atomicAdd(M1r + off + g, r0);
                                atomicAdd(M1r + 192 + off + g, r1);
                                atomicAdd(M1r + 384 + off + g, r2);
                            }
                        }
                        cur = rcvj; r0 = r1 = r2 = 0.f;
                    }
                    const float tv = xt[w][j][gl];
                    if (c == 0) {
                        r0 += ld0[u] * attr_s[w][0][j] * tv;
                    } else if (c == 1) {
                        r0 += (ld0[u] * attr_s[w][1][j] + ld1[u] * attr_s[w][2][j]
                               + ld2[u] * attr_s[w][3][j]) * (INV_SQRT3 * tv);
                    } else if (c == 2) {
                        const float sstv = ld0[u] * tv;
                        r0 += sstv * attr_s[w][1][j];
                        r1 += sstv * attr_s[w][2][j];
                        r2 += sstv * attr_s[w][3][j];
                    } else if (c == 3) {
                        const float a0tv = attr_s[w][0][j] * tv;
                        r0 += ld0[u] * a0tv;
                        r1 += ld1[u] * a0tv;
                        r2 += ld2[u] * a0tv;
                    } else {
                        const float a1j = attr_s[w][1][j];
                        const float a2j = attr_s[w][2][j];
                        const float a3j = attr_s[w][3][j];
                        const float s2t = INV_SQRT2 * tv;
                        r0 += (ld1[u] * a3j - ld2[u] * a2j) * s2t;
                        r1 += (ld2[u] * a1j - ld0[u] * a3j) * s2t;
                        r2 += (ld0[u] * a2j - ld1[u] * a1j) * s2t;
                    }
                }
            }
            // final flush
            if (cur >= 0) {
                if (c == 0)      atomicAdd(&M0[(size_t)cur * 128 + g], r0);
                else if (c == 1) atomicAdd(&M0[(size_t)cur * 128 + 64 + g], r0);
                else {
                    float* M1r = M1 + (size_t)cur * 576;
                    const int off = (c == 2) ? 0 : (c == 3) ? 64 : 128;
                    atomicAdd(M1r + off + g, r0);
                    atomicAdd(M1r + 192 + off + g, r1);
                    atomicAdd(M1r + 384 + off + g, r2);
                }
            }
        }
    }
}

// ---------------------------------------------------------------------------
// Kernel: per-node output projections.
// ---------------------------------------------------------------------------
__global__ __launch_bounds__(256) void out_kernel(
    const float* __restrict__ M0,
    const float* __restrict__ M1,
    const float* __restrict__ Wl0,
    const float* __restrict__ Wl1,
    float* __restrict__ out) {
    const int n = blockIdx.x;
    const int t = threadIdx.x;
    __shared__ float m0[128];
    __shared__ float m1[3][192];
    __shared__ float o_lds[256];

    if (t < 128) m0[t] = M0[(size_t)n * 128 + t];
    for (int i = t; i < 576; i += 256) m1[i / 192][i % 192] = M1[(size_t)n * 576 + i];
    __syncthreads();

    const int c = t >> 6;
    const int g = t & 63;
    float acc = 0.f;
    if (c == 0) {
#pragma unroll 8
        for (int k = 0; k < 128; ++k) acc += m0[k] * Wl0[k * 64 + g];
    } else {
        const float* m = m1[c - 1];
#pragma unroll 8
        for (int k = 0; k < 192; ++k) acc += m[k] * Wl1[k * 64 + g];
    }
    o_lds[g * 4 + c] = acc * INV_AVG;
    __syncthreads();
    out[(size_t)n * 256 + t] = o_lds[t];
}

extern "C" void kernel_launch(void* const* d_in, const int* in_sizes, int n_in,
                              void* d_out, int out_size, void* d_ws, size_t ws_size,
                              hipStream_t stream) {
    const float* node_feats = (const float*)d_in[0];
    const float* edge_attrs = (const float*)d_in[1];
    const float* edge_feats = (const float*)d_in[2];
    const float* lengths    = (const float*)d_in[3];
    const int*   edge_index = (const int*)d_in[4];
    const float* Wsc   = (const float*)d_in[5];
    const float* Wup_s = (const float*)d_in[6];
    const float* Wup_v = (const float*)d_in[7];
    const float* W1 = (const float*)d_in[8];
    const float* b1 = (const float*)d_in[9];
    const float* W2 = (const float*)d_in[10];
    const float* b2 = (const float*)d_in[11];
    const float* W3 = (const float*)d_in[12];
    const float* Wl0 = (const float*)d_in[13];
    const float* Wl1 = (const float*)d_in[14];

    float* ws  = (float*)d_ws;
    float* NS  = ws;                            // N*64
    float* SUP = NS  + (size_t)N_NODES * 64;    // N*64
    float* VUP = SUP + (size_t)N_NODES * 64;    // N*192
    float* M0  = VUP + (size_t)N_NODES * 192;   // N*128
    float* M1  = M0  + (size_t)N_NODES * 128;   // N*576
    int* cnt  = (int*)M0;                       // aliases M0 (wiped later)
    int* offs = cnt + N_NODES;
    int* perm = (int*)d_out;                    // dead until out_kernel

    // 1) build rcv-sorted permutation
    hipMemsetAsync(cnt, 0, N_NODES * sizeof(int), stream);
    hist_kernel<<<E_EDGES / 256, 256, 0, stream>>>(edge_index, cnt);
    scan_kernel<<<1, 256, 0, stream>>>(cnt, offs);
    perm_kernel<<<E_EDGES / 256, 256, 0, stream>>>(edge_index, offs, perm);

    // 2) zero accumulators (also wipes cnt/offs aliases)
    hipMemsetAsync(M0, 0, (size_t)N_NODES * (128 + 576) * sizeof(float), stream);

    // 3) main pipeline
    node_kernel<<<N_NODES, 64, 0, stream>>>(node_feats, Wsc, Wup_s, Wup_v, NS, SUP, VUP);
    edge_kernel<<<E_EDGES / (64 * WPB), 64 * WPB, 0, stream>>>(
        edge_attrs, edge_feats, lengths, edge_index, perm,
        W1, b1, W2, b2, W3, NS, SUP, VUP, M0, M1);
    out_kernel<<<N_NODES, 256, 0, stream>>>(M0, M1, Wl0, Wl1, (float*)d_out);
}

// Round 11
// 722.453 us; speedup vs baseline: 1.1193x; 1.1193x over previous
//
#include <hip/hip_runtime.h>

#define F 64
#define N_NODES 8192
#define E_EDGES 262144
#define EF 32
#define HID 64
#define INV_AVG (1.0f/32.0f)
#define INV_SQRT3 0.57735026918962576f
#define INV_SQRT2 0.70710678118654752f

__device__ __forceinline__ float silu(float x) {
    return x / (1.0f + __expf(-x));
}

// ---------------------------------------------------------------------------
// Sort prologue: counting sort of edges by rcv.
// ---------------------------------------------------------------------------
__global__ __launch_bounds__(256) void hist_kernel(
    const int* __restrict__ edge_index, int* __restrict__ cnt) {
    const int e = blockIdx.x * 256 + threadIdx.x;
    atomicAdd(&cnt[edge_index[E_EDGES + e]], 1);
}

__global__ __launch_bounds__(256) void scan_kernel(
    const int* __restrict__ cnt, int* __restrict__ offs) {
    __shared__ int part[256];
    const int t = threadIdx.x;
    int local[32];
    int s = 0;
#pragma unroll
    for (int i = 0; i < 32; ++i) { local[i] = s; s += cnt[t * 32 + i]; }
    part[t] = s;
    __syncthreads();
    for (int d = 1; d < 256; d <<= 1) {
        int v = (t >= d) ? part[t - d] : 0;
        __syncthreads();
        part[t] += v;
        __syncthreads();
    }
    const int prefix = (t == 0) ? 0 : part[t - 1];
#pragma unroll
    for (int i = 0; i < 32; ++i) offs[t * 32 + i] = prefix + local[i];
}

__global__ __launch_bounds__(256) void perm_kernel(
    const int* __restrict__ edge_index, int* __restrict__ offs,
    int* __restrict__ perm) {
    const int e = blockIdx.x * 256 + threadIdx.x;
    const int pos = atomicAdd(&offs[edge_index[E_EDGES + e]], 1);
    perm[pos] = e;
}

// ---------------------------------------------------------------------------
// Kernel: node transforms.  NS = s@Wsc, SUP = s@Wup_s, VUP[n][c][g] = v@Wup_v
// ---------------------------------------------------------------------------
__global__ __launch_bounds__(64) void node_kernel(
    const float* __restrict__ node_feats,
    const float* __restrict__ Wsc,
    const float* __restrict__ Wup_s,
    const float* __restrict__ Wup_v,
    float* __restrict__ NS,
    float* __restrict__ SUP,
    float* __restrict__ VUP) {
    const int n = blockIdx.x;
    const int g = threadIdx.x;
    __shared__ float s_lds[64];
    __shared__ float v_lds[3][64];

    const float* nf = node_feats + (size_t)n * 256;
    s_lds[g] = nf[g];
    v_lds[0][g] = nf[64 + g * 3 + 0];
    v_lds[1][g] = nf[64 + g * 3 + 1];
    v_lds[2][g] = nf[64 + g * 3 + 2];
    __syncthreads();

    float ns = 0.f, su = 0.f, vu0 = 0.f, vu1 = 0.f, vu2 = 0.f;
#pragma unroll 8
    for (int k = 0; k < 64; ++k) {
        const float sk = s_lds[k];
        ns += sk * Wsc[k * 64 + g];
        su += sk * Wup_s[k * 64 + g];
        const float w = Wup_v[k * 64 + g];
        vu0 += v_lds[0][k] * w;
        vu1 += v_lds[1][k] * w;
        vu2 += v_lds[2][k] * w;
    }
    NS[n * 64 + g] = ns;
    SUP[n * 64 + g] = su;
    VUP[(n * 3 + 0) * 64 + g] = vu0;
    VUP[(n * 3 + 1) * 64 + g] = vu1;
    VUP[(n * 3 + 2) * 64 + g] = vu2;
}

// ---------------------------------------------------------------------------
// Fused edge kernel: ONE wave per block, lane = edge, rcv-sorted.
// Weights staged per-tile into LDS via coalesced float4 vector loads and
// consumed as uniform-address ds_read broadcasts — replaces the serialized
// s_load weight path (rounds 8/9: VALUBusy 29%, 90% stall). X-gather and
// W-stage latencies overlap under one barrier. All register arrays statically
// indexed (rule #20); run-aggregated atomic scatter over rcv-sorted edges.
// ---------------------------------------------------------------------------
#define BATCH 4
__global__ __launch_bounds__(64, 2) void edge_kernel(
    const float* __restrict__ edge_attrs,
    const float* __restrict__ edge_feats,
    const float* __restrict__ lengths,
    const int*   __restrict__ edge_index,
    const int*   __restrict__ perm,
    const float* __restrict__ W1, const float* __restrict__ b1,
    const float* __restrict__ W2, const float* __restrict__ b2,
    const float* __restrict__ W3,
    const float* __restrict__ NS,
    const float* __restrict__ SUP,
    const float* __restrict__ VUP,
    float* __restrict__ M0,
    float* __restrict__ M1) {
    const int lane = threadIdx.x;        // 0..63
    const int e0   = blockIdx.x * 64;

    __shared__ float  xt[64][33];        // X staging / transpose / h2-stash
    __shared__ float4 wb4[512];          // 8KB weight tile (float4-aligned)
    __shared__ int    snd_s[64];
    __shared__ int    rcv_s[64];
    __shared__ int    pe_s[64];
    __shared__ float  attr_s[4][64];
    float* wb = (float*)wb4;

    // ---- edge metadata (sorted order) ----
    const int pe  = perm[e0 + lane];
    const int snd = edge_index[pe];
    const int rcv = edge_index[E_EDGES + pe];
    const float len = lengths[pe];
    const float4 a4 = ((const float4*)edge_attrs)[pe];
    snd_s[lane] = snd;
    rcv_s[lane] = rcv;
    pe_s[lane]  = pe;
    attr_s[0][lane] = a4.x;
    attr_s[1][lane] = a4.y;
    attr_s[2][lane] = a4.z;
    attr_s[3][lane] = a4.w;
    __syncthreads();

    const int kk0 = lane & 31;
    const int jh  = lane >> 5;

    // ---- layer 1: 161 -> 64, acc[g] in VGPRs, W tiles via LDS ----
    float acc[64];
#pragma unroll
    for (int g = 0; g < 64; ++g) acc[g] = b1[g];

#pragma unroll
    for (int t = 0; t < 5; ++t) {
        // stage X: 64 edges x 32 features, 4-wide load batching
        for (int i0 = 0; i0 < 32; i0 += BATCH) {
            float tmp[BATCH];
#pragma unroll
            for (int u = 0; u < BATCH; ++u) {
                const int j = 2 * (i0 + u) + jh;
                if (t < 4) {
                    const int node = (t < 2) ? snd_s[j] : rcv_s[j];
                    tmp[u] = NS[node * 64 + (t & 1) * 32 + kk0];
                } else {
                    tmp[u] = edge_feats[(size_t)pe_s[j] * EF + kk0];
                }
            }
#pragma unroll
            for (int u = 0; u < BATCH; ++u) xt[2 * (i0 + u) + jh][kk0] = tmp[u];
        }
        // stage W1 tile (rows 32t..32t+32, contiguous 8KB), coalesced float4
#pragma unroll
        for (int i = 0; i < 8; ++i)
            wb4[i * 64 + lane] = ((const float4*)W1)[t * 512 + i * 64 + lane];
        __syncthreads();
        for (int kk = 0; kk < 32; ++kk) {
            const float x = xt[lane][kk];
            const float* wr = &wb[kk * 64];          // uniform -> ds broadcast
#pragma unroll
            for (int g = 0; g < 64; ++g) acc[g] += x * wr[g];
        }
        __syncthreads();
    }
    {   // k = 160: length (one row; uniform s_load is fine one-off)
        const float* wr = W1 + 160 * 64;
#pragma unroll
        for (int g = 0; g < 64; ++g) acc[g] += len * wr[g];
    }
#pragma unroll
    for (int k = 0; k < 64; ++k) acc[k] = silu(acc[k]);   // h1 in regs

    // ---- layer 2: 64 -> 64 in two 32-g chunks; W2 tiles via LDS ----
    for (int ch = 0; ch < 2; ++ch) {
        const int gbase = (ch == 0) ? 32 : 0;
        float acc2[32];
#pragma unroll
        for (int gg = 0; gg < 32; ++gg) acc2[gg] = b2[gbase + gg];
#pragma unroll
        for (int tk = 0; tk < 2; ++tk) {
            __syncthreads();                         // wb free of prev reader
#pragma unroll
            for (int i = 0; i < 8; ++i)
                wb4[i * 64 + lane] = ((const float4*)W2)[tk * 512 + i * 64 + lane];
            __syncthreads();
#pragma unroll
            for (int kk = 0; kk < 32; ++kk) {        // acc[] index static
                const float hk = acc[tk * 32 + kk];
#pragma unroll
                for (int gg = 0; gg < 32; ++gg) acc2[gg] += hk * wb[kk * 64 + gbase + gg];
            }
        }
        if (ch == 0) {
#pragma unroll
            for (int gg = 0; gg < 32; ++gg) xt[lane][gg] = silu(acc2[gg]);
        } else {
#pragma unroll
            for (int gg = 0; gg < 32; ++gg) acc[gg] = silu(acc2[gg]);
#pragma unroll
            for (int gg = 0; gg < 32; ++gg) acc[32 + gg] = xt[lane][gg];
        }
    }
    // acc[] now holds h2.

    // ---- layer 3 (ten 32-wide chunks): W3 slice via LDS + transpose + scatter
    const int halfsel = lane >> 5;
    const int gl      = lane & 31;

    for (int c = 0; c < 5; ++c) {
        for (int hh = 0; hh < 2; ++hh) {
            const int cbase = c * 64 + hh * 32;
            __syncthreads();                         // wb free of prev reader
            // stage W3 tile [64 k][32 g]: row k at W3 + k*320 + cbase
#pragma unroll
            for (int i = 0; i < 8; ++i) {
                const int idx = i * 64 + lane;       // 0..511 float4s
                const int k = idx >> 3, q = idx & 7;
                wb4[idx] = *(const float4*)(W3 + k * 320 + cbase + q * 4);
            }
            __syncthreads();

            float acc3[32];
#pragma unroll
            for (int gg = 0; gg < 32; ++gg) acc3[gg] = 0.f;
#pragma unroll
            for (int k = 0; k < 64; ++k) {           // acc[] index static
                const float hk = acc[k];
#pragma unroll
                for (int gg = 0; gg < 32; ++gg) acc3[gg] += hk * wb[k * 32 + gg];
            }
            // transpose to lane=feature
            __syncthreads();
#pragma unroll
            for (int gg = 0; gg < 32; ++gg) xt[lane][gg] = acc3[gg];
            __syncthreads();

            const int g = cbase - c * 64 + gl;       // hh*32 + gl
            int   cur = -1;
            float r0 = 0.f, r1 = 0.f, r2 = 0.f;
            for (int u0 = 0; u0 < 32; u0 += BATCH) {
                float ld0[BATCH], ld1[BATCH], ld2[BATCH];
#pragma unroll
                for (int u = 0; u < BATCH; ++u) {
                    const int j = 32 * halfsel + u0 + u;
                    const int sndj = snd_s[j];
                    if (c == 0 || c == 2) {
                        ld0[u] = SUP[sndj * 64 + g];
                    } else {
                        ld0[u] = VUP[(sndj * 3 + 0) * 64 + g];
                        ld1[u] = VUP[(sndj * 3 + 1) * 64 + g];
                        ld2[u] = VUP[(sndj * 3 + 2) * 64 + g];
                    }
                }
#pragma unroll
                for (int u = 0; u < BATCH; ++u) {
                    const int j = 32 * halfsel + u0 + u;
                    const int rcvj = rcv_s[j];
                    if (rcvj != cur) {
                        if (cur >= 0) {
                            if (c == 0)      atomicAdd(&M0[(size_t)cur * 128 + g], r0);
                            else if (c == 1) atomicAdd(&M0[(size_t)cur * 128 + 64 + g], r0);
                            else {
                                float* M1r = M1 + (size_t)cur * 576;
                                const int off = (c == 2) ? 0 : (c == 3) ? 64 : 128;
                                atomicAdd(M1r + off + g, r0);
                                atomicAdd(M1r + 192 + off + g, r1);
                                atomicAdd(M1r + 384 + off + g, r2);
                            }
                        }
                        cur = rcvj; r0 = r1 = r2 = 0.f;
                    }
                    const float tv = xt[j][gl];
                    if (c == 0) {
                        r0 += ld0[u] * attr_s[0][j] * tv;
                    } else if (c == 1) {
                        r0 += (ld0[u] * attr_s[1][j] + ld1[u] * attr_s[2][j]
                               + ld2[u] * attr_s[3][j]) * (INV_SQRT3 * tv);
                    } else if (c == 2) {
                        const float sstv = ld0[u] * tv;
                        r0 += sstv * attr_s[1][j];
                        r1 += sstv * attr_s[2][j];
                        r2 += sstv * attr_s[3][j];
                    } else if (c == 3) {
                        const float a0tv = attr_s[0][j] * tv;
                        r0 += ld0[u] * a0tv;
                        r1 += ld1[u] * a0tv;
                        r2 += ld2[u] * a0tv;
                    } else {
                        const float a1j = attr_s[1][j];
                        const float a2j = attr_s[2][j];
                        const float a3j = attr_s[3][j];
                        const float s2t = INV_SQRT2 * tv;
                        r0 += (ld1[u] * a3j - ld2[u] * a2j) * s2t;
                        r1 += (ld2[u] * a1j - ld0[u] * a3j) * s2t;
                        r2 += (ld0[u] * a2j - ld1[u] * a1j) * s2t;
                    }
                }
            }
            if (cur >= 0) {
                if (c == 0)      atomicAdd(&M0[(size_t)cur * 128 + g], r0);
                else if (c == 1) atomicAdd(&M0[(size_t)cur * 128 + 64 + g], r0);
                else {
                    float* M1r = M1 + (size_t)cur * 576;
                    const int off = (c == 2) ? 0 : (c == 3) ? 64 : 128;
                    atomicAdd(M1r + off + g, r0);
                    atomicAdd(M1r + 192 + off + g, r1);
                    atomicAdd(M1r + 384 + off + g, r2);
                }
            }
        }
    }
}

// ---------------------------------------------------------------------------
// Kernel: per-node output projections.
// ---------------------------------------------------------------------------
__global__ __launch_bounds__(256) void out_kernel(
    const float* __restrict__ M0,
    const float* __restrict__ M1,
    const float* __restrict__ Wl0,
    const float* __restrict__ Wl1,
    float* __restrict__ out) {
    const int n = blockIdx.x;
    const int t = threadIdx.x;
    __shared__ float m0[128];
    __shared__ float m1[3][192];
    __shared__ float o_lds[256];

    if (t < 128) m0[t] = M0[(size_t)n * 128 + t];
    for (int i = t; i < 576; i += 256) m1[i / 192][i % 192] = M1[(size_t)n * 576 + i];
    __syncthreads();

    const int c = t >> 6;
    const int g = t & 63;
    float acc = 0.f;
    if (c == 0) {
#pragma unroll 8
        for (int k = 0; k < 128; ++k) acc += m0[k] * Wl0[k * 64 + g];
    } else {
        const float* m = m1[c - 1];
#pragma unroll 8
        for (int k = 0; k < 192; ++k) acc += m[k] * Wl1[k * 64 + g];
    }
    o_lds[g * 4 + c] = acc * INV_AVG;
    __syncthreads();
    out[(size_t)n * 256 + t] = o_lds[t];
}

extern "C" void kernel_launch(void* const* d_in, const int* in_sizes, int n_in,
                              void* d_out, int out_size, void* d_ws, size_t ws_size,
                              hipStream_t stream) {
    const float* node_feats = (const float*)d_in[0];
    const float* edge_attrs = (const float*)d_in[1];
    const float* edge_feats = (const float*)d_in[2];
    const float* lengths    = (const float*)d_in[3];
    const int*   edge_index = (const int*)d_in[4];
    const float* Wsc   = (const float*)d_in[5];
    const float* Wup_s = (const float*)d_in[6];
    const float* Wup_v = (const float*)d_in[7];
    const float* W1 = (const float*)d_in[8];
    const float* b1 = (const float*)d_in[9];
    const float* W2 = (const float*)d_in[10];
    const float* b2 = (const float*)d_in[11];
    const float* W3 = (const float*)d_in[12];
    const float* Wl0 = (const float*)d_in[13];
    const float* Wl1 = (const float*)d_in[14];

    float* ws  = (float*)d_ws;
    float* NS  = ws;                            // N*64
    float* SUP = NS  + (size_t)N_NODES * 64;    // N*64
    float* VUP = SUP + (size_t)N_NODES * 64;    // N*192
    float* M0  = VUP + (size_t)N_NODES * 192;   // N*128
    float* M1  = M0  + (size_t)N_NODES * 128;   // N*576
    int* cnt  = (int*)M0;                       // aliases M0 (wiped later)
    int* offs = cnt + N_NODES;
    int* perm = (int*)d_out;                    // dead until out_kernel

    // 1) build rcv-sorted permutation
    hipMemsetAsync(cnt, 0, N_NODES * sizeof(int), stream);
    hist_kernel<<<E_EDGES / 256, 256, 0, stream>>>(edge_index, cnt);
    scan_kernel<<<1, 256, 0, stream>>>(cnt, offs);
    perm_kernel<<<E_EDGES / 256, 256, 0, stream>>>(edge_index, offs, perm);

    // 2) zero accumulators (also wipes cnt/offs aliases)
    hipMemsetAsync(M0, 0, (size_t)N_NODES * (128 + 576) * sizeof(float), stream);

    // 3) main pipeline
    node_kernel<<<N_NODES, 64, 0, stream>>>(node_feats, Wsc, Wup_s, Wup_v, NS, SUP, VUP);
    edge_kernel<<<E_EDGES / 64, 64, 0, stream>>>(
        edge_attrs, edge_feats, lengths, edge_index, perm,
        W1, b1, W2, b2, W3, NS, SUP, VUP, M0, M1);
    out_kernel<<<N_NODES, 256, 0, stream>>>(M0, M1, Wl0, Wl1, (float*)d_out);
}

// Round 12
// 575.726 us; speedup vs baseline: 1.4046x; 1.2549x over previous
//
#include <hip/hip_runtime.h>

#define F 64
#define N_NODES 8192
#define E_EDGES 262144
#define EF 32
#define HID 64
#define INV_AVG (1.0f/32.0f)
#define INV_SQRT3 0.57735026918962576f
#define INV_SQRT2 0.70710678118654752f
#define PAD 68   // row stride (floats): 272B, 16B-aligned rows, bank-spreading

__device__ __forceinline__ float silu(float x) {
    return x / (1.0f + __expf(-x));
}

// ---------------------------------------------------------------------------
// Sort prologue: counting sort of edges by rcv.
// ---------------------------------------------------------------------------
__global__ __launch_bounds__(256) void hist_kernel(
    const int* __restrict__ edge_index, int* __restrict__ cnt) {
    const int e = blockIdx.x * 256 + threadIdx.x;
    atomicAdd(&cnt[edge_index[E_EDGES + e]], 1);
}

__global__ __launch_bounds__(256) void scan_kernel(
    const int* __restrict__ cnt, int* __restrict__ offs) {
    __shared__ int part[256];
    const int t = threadIdx.x;
    int local[32];
    int s = 0;
#pragma unroll
    for (int i = 0; i < 32; ++i) { local[i] = s; s += cnt[t * 32 + i]; }
    part[t] = s;
    __syncthreads();
    for (int d = 1; d < 256; d <<= 1) {
        int v = (t >= d) ? part[t - d] : 0;
        __syncthreads();
        part[t] += v;
        __syncthreads();
    }
    const int prefix = (t == 0) ? 0 : part[t - 1];
#pragma unroll
    for (int i = 0; i < 32; ++i) offs[t * 32 + i] = prefix + local[i];
}

__global__ __launch_bounds__(256) void perm_kernel(
    const int* __restrict__ edge_index, int* __restrict__ offs,
    int* __restrict__ perm) {
    const int e = blockIdx.x * 256 + threadIdx.x;
    const int pos = atomicAdd(&offs[edge_index[E_EDGES + e]], 1);
    perm[pos] = e;
}

// ---------------------------------------------------------------------------
// Kernel: node transforms.  NS = s@Wsc, SUP = s@Wup_s, VUP[n][c][g] = v@Wup_v
// ---------------------------------------------------------------------------
__global__ __launch_bounds__(64) void node_kernel(
    const float* __restrict__ node_feats,
    const float* __restrict__ Wsc,
    const float* __restrict__ Wup_s,
    const float* __restrict__ Wup_v,
    float* __restrict__ NS,
    float* __restrict__ SUP,
    float* __restrict__ VUP) {
    const int n = blockIdx.x;
    const int g = threadIdx.x;
    __shared__ float s_lds[64];
    __shared__ float v_lds[3][64];

    const float* nf = node_feats + (size_t)n * 256;
    s_lds[g] = nf[g];
    v_lds[0][g] = nf[64 + g * 3 + 0];
    v_lds[1][g] = nf[64 + g * 3 + 1];
    v_lds[2][g] = nf[64 + g * 3 + 2];
    __syncthreads();

    float ns = 0.f, su = 0.f, vu0 = 0.f, vu1 = 0.f, vu2 = 0.f;
#pragma unroll 8
    for (int k = 0; k < 64; ++k) {
        const float sk = s_lds[k];
        ns += sk * Wsc[k * 64 + g];
        su += sk * Wup_s[k * 64 + g];
        const float w = Wup_v[k * 64 + g];
        vu0 += v_lds[0][k] * w;
        vu1 += v_lds[1][k] * w;
        vu2 += v_lds[2][k] * w;
    }
    NS[n * 64 + g] = ns;
    SUP[n * 64 + g] = su;
    VUP[(n * 3 + 0) * 64 + g] = vu0;
    VUP[(n * 3 + 1) * 64 + g] = vu1;
    VUP[(n * 3 + 2) * 64 + g] = vu2;
}

__device__ __forceinline__ void flush_run(int c, int cur, int gS,
                                          float r0, float r1, float r2,
                                          float* __restrict__ M0,
                                          float* __restrict__ M1) {
    if (cur < 0) return;
    if (c == 0)      atomicAdd(&M0[(size_t)cur * 128 + gS], r0);
    else if (c == 1) atomicAdd(&M0[(size_t)cur * 128 + 64 + gS], r0);
    else {
        float* M1r = M1 + (size_t)cur * 576;
        const int off = (c == 2) ? 0 : (c == 3) ? 64 : 128;
        atomicAdd(M1r + off + gS, r0);
        atomicAdd(M1r + 192 + off + gS, r1);
        atomicAdd(M1r + 384 + off + gS, r2);
    }
}

// ---------------------------------------------------------------------------
// Fused edge kernel, GEMM-tiled: 256 threads per 64-edge block.
// 4x4 register blocking (16 acc/thread, 16x16 thread grid covers 64x64),
// operands via b128 LDS reads (pad 68 -> aligned rows, spread banks).
// Layers: X-gather -> GEMM1(161->64) -> silu -> GEMM2(64->64) -> silu ->
// per c-chunk: GEMM3(64->64) -> tpw LDS -> 4-wave scatter (16 edges each,
// coalesced SUP/VUP row gathers, run-aggregated atomics over sorted rcv).
// ---------------------------------------------------------------------------
__global__ __launch_bounds__(256, 3) void edge_kernel(
    const float* __restrict__ edge_attrs,
    const float* __restrict__ edge_feats,
    const float* __restrict__ lengths,
    const int*   __restrict__ edge_index,
    const int*   __restrict__ perm,
    const float* __restrict__ W1, const float* __restrict__ b1,
    const float* __restrict__ W2, const float* __restrict__ b2,
    const float* __restrict__ W3,
    const float* __restrict__ NS,
    const float* __restrict__ SUP,
    const float* __restrict__ VUP,
    float* __restrict__ M0,
    float* __restrict__ M1) {
    const int t  = threadIdx.x;
    const int e0 = blockIdx.x * 64;

    __shared__ float tw[64][PAD];   // rows 0-31: xT staging; later tpw[j][g]
    __shared__ float wb[32][PAD];   // weight tile [k][g]
    __shared__ float hT[64][PAD];   // h1T/h2T [feature][j]
    __shared__ int   snd_s[64], rcv_s[64], pe_s[64];
    __shared__ float len_s[64], attr_s[4][64], b1s[64], b2s[64], w160[64];

    // ---- metadata + small stages ----
    if (t < 64) {
        const int pe = perm[e0 + t];
        pe_s[t]  = pe;
        snd_s[t] = edge_index[pe];
        rcv_s[t] = edge_index[E_EDGES + pe];
        len_s[t] = lengths[pe];
        const float4 a4 = ((const float4*)edge_attrs)[pe];
        attr_s[0][t] = a4.x; attr_s[1][t] = a4.y;
        attr_s[2][t] = a4.z; attr_s[3][t] = a4.w;
    } else if (t < 128) {
        b1s[t - 64] = b1[t - 64];
    } else if (t < 192) {
        b2s[t - 128] = b2[t - 128];
    } else {
        w160[t - 192] = W1[160 * 64 + (t - 192)];
    }
    __syncthreads();

    const int j0 = (t & 15) * 4;        // output tile: 4 edges
    const int g0 = (t >> 4) * 4;        // output tile: 4 features
    const int jx  = t & 63;             // staging: edge
    const int kk0 = (t >> 6) * 8;       // staging: 8 k-rows per wave
    const int wr_row = t >> 3;          // wb staging: row 0..31
    const int wr_g   = (t & 7) * 4;     // wb staging: col (and +32)

    // ---- layer 1: 161 -> 64 ----
    float acc1[4][4];
#pragma unroll
    for (int u = 0; u < 4; ++u)
#pragma unroll
        for (int v = 0; v < 4; ++v) acc1[u][v] = b1s[g0 + v];

    for (int tt = 0; tt < 5; ++tt) {
        // stage xT (transposed): features tt*32+kk for all 64 edges
        {
            float4 fa, fb;
            if (tt < 4) {
                const int node = (tt < 2) ? snd_s[jx] : rcv_s[jx];
                const float* src = NS + node * 64 + (tt & 1) * 32;
                fa = *(const float4*)(src + kk0);
                fb = *(const float4*)(src + kk0 + 4);
            } else {
                const float* src = edge_feats + (size_t)pe_s[jx] * EF;
                fa = *(const float4*)(src + kk0);
                fb = *(const float4*)(src + kk0 + 4);
            }
            tw[kk0 + 0][jx] = fa.x; tw[kk0 + 1][jx] = fa.y;
            tw[kk0 + 2][jx] = fa.z; tw[kk0 + 3][jx] = fa.w;
            tw[kk0 + 4][jx] = fb.x; tw[kk0 + 5][jx] = fb.y;
            tw[kk0 + 6][jx] = fb.z; tw[kk0 + 7][jx] = fb.w;
        }
        // stage wb = W1 rows tt*32 .. +31
        {
            const float* src = W1 + (tt * 32 + wr_row) * 64;
            *(float4*)&wb[wr_row][wr_g]      = *(const float4*)(src + wr_g);
            *(float4*)&wb[wr_row][wr_g + 32] = *(const float4*)(src + wr_g + 32);
        }
        __syncthreads();
#pragma unroll
        for (int kk = 0; kk < 32; ++kk) {
            const float4 x4 = *(const float4*)&tw[kk][j0];
            const float4 w4 = *(const float4*)&wb[kk][g0];
            const float xv[4] = {x4.x, x4.y, x4.z, x4.w};
            const float wv[4] = {w4.x, w4.y, w4.z, w4.w};
#pragma unroll
            for (int u = 0; u < 4; ++u)
#pragma unroll
                for (int v = 0; v < 4; ++v) acc1[u][v] += xv[u] * wv[v];
        }
        __syncthreads();
    }
    // k = 160: lengths
#pragma unroll
    for (int u = 0; u < 4; ++u) {
        const float lj = len_s[j0 + u];
#pragma unroll
        for (int v = 0; v < 4; ++v) acc1[u][v] += lj * w160[g0 + v];
    }
    // silu -> h1T[g][j]
#pragma unroll
    for (int v = 0; v < 4; ++v) {
        float4 hv;
        hv.x = silu(acc1[0][v]); hv.y = silu(acc1[1][v]);
        hv.z = silu(acc1[2][v]); hv.w = silu(acc1[3][v]);
        *(float4*)&hT[g0 + v][j0] = hv;
    }

    // ---- layer 2: 64 -> 64 ----
    float acc2[4][4];
#pragma unroll
    for (int u = 0; u < 4; ++u)
#pragma unroll
        for (int v = 0; v < 4; ++v) acc2[u][v] = b2s[g0 + v];

    for (int hh = 0; hh < 2; ++hh) {
        {
            const float* src = W2 + (hh * 32 + wr_row) * 64;
            *(float4*)&wb[wr_row][wr_g]      = *(const float4*)(src + wr_g);
            *(float4*)&wb[wr_row][wr_g + 32] = *(const float4*)(src + wr_g + 32);
        }
        __syncthreads();   // also publishes h1T on first iteration
#pragma unroll
        for (int kk = 0; kk < 32; ++kk) {
            const float4 x4 = *(const float4*)&hT[hh * 32 + kk][j0];
            const float4 w4 = *(const float4*)&wb[kk][g0];
            const float xv[4] = {x4.x, x4.y, x4.z, x4.w};
            const float wv[4] = {w4.x, w4.y, w4.z, w4.w};
#pragma unroll
            for (int u = 0; u < 4; ++u)
#pragma unroll
                for (int v = 0; v < 4; ++v) acc2[u][v] += xv[u] * wv[v];
        }
        __syncthreads();
    }
    // silu -> h2T[g][j] (overwrite hT; all reads done at last barrier)
#pragma unroll
    for (int v = 0; v < 4; ++v) {
        float4 hv;
        hv.x = silu(acc2[0][v]); hv.y = silu(acc2[1][v]);
        hv.z = silu(acc2[2][v]); hv.w = silu(acc2[3][v]);
        *(float4*)&hT[g0 + v][j0] = hv;
    }

    // ---- layer 3 + tensor product + scatter, per 64-wide chunk c ----
    const int gS = t & 63;
    const int wS = t >> 6;

    for (int c = 0; c < 5; ++c) {
        float acc3[4][4];
#pragma unroll
        for (int u = 0; u < 4; ++u)
#pragma unroll
            for (int v = 0; v < 4; ++v) acc3[u][v] = 0.f;

        for (int hh = 0; hh < 2; ++hh) {
            {
                const float* src = W3 + (hh * 32 + wr_row) * 320 + c * 64;
                *(float4*)&wb[wr_row][wr_g]      = *(const float4*)(src + wr_g);
                *(float4*)&wb[wr_row][wr_g + 32] = *(const float4*)(src + wr_g + 32);
            }
            __syncthreads();   // publishes h2T (c=0) / joins prev scatter
#pragma unroll
            for (int kk = 0; kk < 32; ++kk) {
                const float4 x4 = *(const float4*)&hT[hh * 32 + kk][j0];
                const float4 w4 = *(const float4*)&wb[kk][g0];
                const float xv[4] = {x4.x, x4.y, x4.z, x4.w};
                const float wv[4] = {w4.x, w4.y, w4.z, w4.w};
#pragma unroll
                for (int u = 0; u < 4; ++u)
#pragma unroll
                    for (int v = 0; v < 4; ++v) acc3[u][v] += xv[u] * wv[v];
            }
            __syncthreads();
        }
        // write tpw[j][g] (tw rows fully free: xT dead since GEMM1)
#pragma unroll
        for (int u = 0; u < 4; ++u) {
            float4 tv4;
            tv4.x = acc3[u][0]; tv4.y = acc3[u][1];
            tv4.z = acc3[u][2]; tv4.w = acc3[u][3];
            *(float4*)&tw[j0 + u][g0] = tv4;
        }
        __syncthreads();

        // scatter: wave wS handles edges [wS*16, wS*16+16), lane = feature gS
        {
            int cur = -1;
            float r0 = 0.f, r1 = 0.f, r2 = 0.f;
            for (int b4 = 0; b4 < 4; ++b4) {
                float l0[4], l1[4], l2[4];
#pragma unroll
                for (int u = 0; u < 4; ++u) {
                    const int j  = wS * 16 + b4 * 4 + u;
                    const int sj = snd_s[j];
                    if (c == 0 || c == 2) {
                        l0[u] = SUP[sj * 64 + gS];
                    } else {
                        l0[u] = VUP[(sj * 3 + 0) * 64 + gS];
                        l1[u] = VUP[(sj * 3 + 1) * 64 + gS];
                        l2[u] = VUP[(sj * 3 + 2) * 64 + gS];
                    }
                }
#pragma unroll
                for (int u = 0; u < 4; ++u) {
                    const int j  = wS * 16 + b4 * 4 + u;
                    const int rj = rcv_s[j];
                    if (rj != cur) {
                        flush_run(c, cur, gS, r0, r1, r2, M0, M1);
                        cur = rj; r0 = r1 = r2 = 0.f;
                    }
                    const float tv = tw[j][gS];
                    if (c == 0) {
                        r0 += l0[u] * attr_s[0][j] * tv;
                    } else if (c == 1) {
                        r0 += (l0[u] * attr_s[1][j] + l1[u] * attr_s[2][j]
                               + l2[u] * attr_s[3][j]) * (INV_SQRT3 * tv);
                    } else if (c == 2) {
                        const float sstv = l0[u] * tv;
                        r0 += sstv * attr_s[1][j];
                        r1 += sstv * attr_s[2][j];
                        r2 += sstv * attr_s[3][j];
                    } else if (c == 3) {
                        const float a0tv = attr_s[0][j] * tv;
                        r0 += l0[u] * a0tv;
                        r1 += l1[u] * a0tv;
                        r2 += l2[u] * a0tv;
                    } else {
                        const float a1j = attr_s[1][j];
                        const float a2j = attr_s[2][j];
                        const float a3j = attr_s[3][j];
                        const float s2t = INV_SQRT2 * tv;
                        r0 += (l1[u] * a3j - l2[u] * a2j) * s2t;
                        r1 += (l2[u] * a1j - l0[u] * a3j) * s2t;
                        r2 += (l0[u] * a2j - l1[u] * a1j) * s2t;
                    }
                }
            }
            flush_run(c, cur, gS, r0, r1, r2, M0, M1);
        }
        __syncthreads();
    }
}

// ---------------------------------------------------------------------------
// Kernel: per-node output projections.
// ---------------------------------------------------------------------------
__global__ __launch_bounds__(256) void out_kernel(
    const float* __restrict__ M0,
    const float* __restrict__ M1,
    const float* __restrict__ Wl0,
    const float* __restrict__ Wl1,
    float* __restrict__ out) {
    const int n = blockIdx.x;
    const int t = threadIdx.x;
    __shared__ float m0[128];
    __shared__ float m1[3][192];
    __shared__ float o_lds[256];

    if (t < 128) m0[t] = M0[(size_t)n * 128 + t];
    for (int i = t; i < 576; i += 256) m1[i / 192][i % 192] = M1[(size_t)n * 576 + i];
    __syncthreads();

    const int c = t >> 6;
    const int g = t & 63;
    float acc = 0.f;
    if (c == 0) {
#pragma unroll 8
        for (int k = 0; k < 128; ++k) acc += m0[k] * Wl0[k * 64 + g];
    } else {
        const float* m = m1[c - 1];
#pragma unroll 8
        for (int k = 0; k < 192; ++k) acc += m[k] * Wl1[k * 64 + g];
    }
    o_lds[g * 4 + c] = acc * INV_AVG;
    __syncthreads();
    out[(size_t)n * 256 + t] = o_lds[t];
}

extern "C" void kernel_launch(void* const* d_in, const int* in_sizes, int n_in,
                              void* d_out, int out_size, void* d_ws, size_t ws_size,
                              hipStream_t stream) {
    const float* node_feats = (const float*)d_in[0];
    const float* edge_attrs = (const float*)d_in[1];
    const float* edge_feats = (const float*)d_in[2];
    const float* lengths    = (const float*)d_in[3];
    const int*   edge_index = (const int*)d_in[4];
    const float* Wsc   = (const float*)d_in[5];
    const float* Wup_s = (const float*)d_in[6];
    const float* Wup_v = (const float*)d_in[7];
    const float* W1 = (const float*)d_in[8];
    const float* b1 = (const float*)d_in[9];
    const float* W2 = (const float*)d_in[10];
    const float* b2 = (const float*)d_in[11];
    const float* W3 = (const float*)d_in[12];
    const float* Wl0 = (const float*)d_in[13];
    const float* Wl1 = (const float*)d_in[14];

    float* ws  = (float*)d_ws;
    float* NS  = ws;                            // N*64
    float* SUP = NS  + (size_t)N_NODES * 64;    // N*64
    float* VUP = SUP + (size_t)N_NODES * 64;    // N*192
    float* M0  = VUP + (size_t)N_NODES * 192;   // N*128
    float* M1  = M0  + (size_t)N_NODES * 128;   // N*576
    int* cnt  = (int*)M0;                       // aliases M0 (wiped later)
    int* offs = cnt + N_NODES;
    int* perm = (int*)d_out;                    // dead until out_kernel

    // 1) build rcv-sorted permutation
    hipMemsetAsync(cnt, 0, N_NODES * sizeof(int), stream);
    hist_kernel<<<E_EDGES / 256, 256, 0, stream>>>(edge_index, cnt);
    scan_kernel<<<1, 256, 0, stream>>>(cnt, offs);
    perm_kernel<<<E_EDGES / 256, 256, 0, stream>>>(edge_index, offs, perm);

    // 2) zero accumulators (also wipes cnt/offs aliases)
    hipMemsetAsync(M0, 0, (size_t)N_NODES * (128 + 576) * sizeof(float), stream);

    // 3) main pipeline
    node_kernel<<<N_NODES, 64, 0, stream>>>(node_feats, Wsc, Wup_s, Wup_v, NS, SUP, VUP);
    edge_kernel<<<E_EDGES / 64, 256, 0, stream>>>(
        edge_attrs, edge_feats, lengths, edge_index, perm,
        W1, b1, W2, b2, W3, NS, SUP, VUP, M0, M1);
    out_kernel<<<N_NODES, 256, 0, stream>>>(M0, M1, Wl0, Wl1, (float*)d_out);
}